// Round 1
// 1053.914 us; speedup vs baseline: 1.0930x; 1.0930x over previous
//
#include <hip/hip_runtime.h>
#include <hip/hip_bf16.h>
#include <stdint.h>

#define EMBED 768
#define NH    12
#define HD    64
#define BB    4
#define SSEQ  2048
#define TOK   (BB*SSEQ)          // 8192 tokens
#define ATT_SCALE 0.125f         // 64^-0.5
#define NT    (SSEQ/64)          // 32 K-tiles

typedef short  short8  __attribute__((ext_vector_type(8)));
typedef float  floatx4 __attribute__((ext_vector_type(4)));

// round-to-nearest-even fp32 -> bf16
__device__ __forceinline__ unsigned short f2bf(float f) {
  unsigned int u = __float_as_uint(f);
  return (unsigned short)((u + 0x7fffu + ((u >> 16) & 1u)) >> 16);
}

// async global->LDS, 16B per lane. LDS dest must be wave-uniform base + lane*16.
__device__ __forceinline__ void gl_lds16(const void* gsrc, void* ldst) {
  __builtin_amdgcn_global_load_lds(
      (__attribute__((address_space(1))) void*)(uintptr_t)gsrc,
      (__attribute__((address_space(3))) void*)ldst, 16, 0, 0);
}

#define VM_WAIT0()  asm volatile("s_waitcnt vmcnt(0)" ::: "memory")
#define VM_WAIT32() asm volatile("s_waitcnt vmcnt(32)" ::: "memory")
#define BARRIER()   asm volatile("s_barrier" ::: "memory")
#define MEMFENCE()  asm volatile("" ::: "memory")

// ---------------------------------------------------------------- fp32->bf16
__global__ void cvtk(const float* __restrict__ x, unsigned short* __restrict__ y, int n4) {
  int i = blockIdx.x * blockDim.x + threadIdx.x;
  if (i < n4) {
    float4 v = ((const float4*)x)[i];
    ushort4 o;
    o.x = f2bf(v.x); o.y = f2bf(v.y); o.z = f2bf(v.z); o.w = f2bf(v.w);
    ((ushort4*)y)[i] = o;
  }
}

// ------------------------------------------------- QKV projection: X @ W^T + b
// Q,K out: [b,h,s,d] bf16.  V out: [b,h,d,s] bf16 (transposed for attn's PV
// B-operand, so attn can stage V^T tiles with gl_lds16 instead of a per-tile
// bank-conflicted LDS transpose).
__global__ __launch_bounds__(256, 2) void gemm_qkv(
    const unsigned short* __restrict__ Xb,
    const unsigned short* __restrict__ Wqb, const unsigned short* __restrict__ Wkb,
    const unsigned short* __restrict__ Wvb,
    const float* __restrict__ bq, const float* __restrict__ bk, const float* __restrict__ bv,
    unsigned short* __restrict__ Qw, unsigned short* __restrict__ Kw,
    unsigned short* __restrict__ Vw)
{
  __shared__ __align__(16) unsigned short As[128*64];
  __shared__ __align__(16) unsigned short Bs[128*64];
  const int z = blockIdx.z;
  const unsigned short* Wb = (z == 0) ? Wqb : (z == 1) ? Wkb : Wvb;
  const float* bias        = (z == 0) ? bq  : (z == 1) ? bk  : bv;
  unsigned short* Out      = (z == 0) ? Qw  : (z == 1) ? Kw  : Vw;

  const int tid = threadIdx.x;
  const int wid = tid >> 6, lane = tid & 63, quad = lane >> 4, l15 = lane & 15;
  const int wm = (wid >> 1) * 64, wn = (wid & 1) * 64;
  const int m0 = blockIdx.y * 128, n0 = blockIdx.x * 128;

  floatx4 acc[4][4] = {};

  for (int k0 = 0; k0 < EMBED; k0 += 64) {
#pragma unroll
    for (int p = 0; p < 4; ++p) {
      int f = p*256 + tid;
      int row = f >> 3, ch = f & 7;
      gl_lds16(Xb + (size_t)(m0+row)*EMBED + k0 + ch*8, &As[f*8]);
      gl_lds16(Wb + (size_t)(n0+row)*EMBED + k0 + ch*8, &Bs[f*8]);
    }
    __syncthreads();
#pragma unroll
    for (int kk = 0; kk < 2; ++kk) {
      short8 af[4], bf[4];
#pragma unroll
      for (int i = 0; i < 4; ++i)
        af[i] = *(const short8*)&As[(wm + i*16 + l15)*64 + kk*32 + quad*8];
#pragma unroll
      for (int j = 0; j < 4; ++j)
        bf[j] = *(const short8*)&Bs[(wn + j*16 + l15)*64 + kk*32 + quad*8];
#pragma unroll
      for (int i = 0; i < 4; ++i)
#pragma unroll
        for (int j = 0; j < 4; ++j)
          acc[i][j] = __builtin_amdgcn_mfma_f32_16x16x32_bf16(af[i], bf[j], acc[i][j], 0, 0, 0);
    }
    __syncthreads();
  }

#pragma unroll
  for (int j = 0; j < 4; ++j) {
    int n = n0 + wn + j*16 + l15;
    float bia = bias[n];
    int h = n >> 6, d = n & 63;
#pragma unroll
    for (int i = 0; i < 4; ++i) {
#pragma unroll
      for (int r = 0; r < 4; ++r) {
        int m = m0 + wm + i*16 + quad*4 + r;          // C/D: row=(lane>>4)*4+reg
        int b = m >> 11, s = m & 2047;
        if (z == 2)   // V^T: [b,h,d,s]
          Out[((size_t)(b*NH + h)*HD + d)*SSEQ + s] = f2bf(acc[i][j][r] + bia);
        else          // Q,K: [b,h,s,d]
          Out[(size_t)(b*NH + h)*SSEQ*HD + (size_t)s*HD + d] = f2bf(acc[i][j][r] + bia);
      }
    }
  }
}

// ------------------------------------------------- O projection: A @ Wo^T + bo
__global__ __launch_bounds__(256, 2) void gemm_o(
    const unsigned short* __restrict__ Ab, const unsigned short* __restrict__ Wb,
    const float* __restrict__ bias, float* __restrict__ Fo)
{
  __shared__ __align__(16) unsigned short As[128*64];
  __shared__ __align__(16) unsigned short Bs[128*64];
  const int tid = threadIdx.x;
  const int wid = tid >> 6, lane = tid & 63, quad = lane >> 4, l15 = lane & 15;
  const int wm = (wid >> 1) * 64, wn = (wid & 1) * 64;
  const int m0 = blockIdx.y * 128, n0 = blockIdx.x * 128;

  floatx4 acc[4][4] = {};

  for (int k0 = 0; k0 < EMBED; k0 += 64) {
#pragma unroll
    for (int p = 0; p < 4; ++p) {
      int f = p*256 + tid;
      int row = f >> 3, ch = f & 7;
      gl_lds16(Ab + (size_t)(m0+row)*EMBED + k0 + ch*8, &As[f*8]);
      gl_lds16(Wb + (size_t)(n0+row)*EMBED + k0 + ch*8, &Bs[f*8]);
    }
    __syncthreads();
#pragma unroll
    for (int kk = 0; kk < 2; ++kk) {
      short8 af[4], bf[4];
#pragma unroll
      for (int i = 0; i < 4; ++i)
        af[i] = *(const short8*)&As[(wm + i*16 + l15)*64 + kk*32 + quad*8];
#pragma unroll
      for (int j = 0; j < 4; ++j)
        bf[j] = *(const short8*)&Bs[(wn + j*16 + l15)*64 + kk*32 + quad*8];
#pragma unroll
      for (int i = 0; i < 4; ++i)
#pragma unroll
        for (int j = 0; j < 4; ++j)
          acc[i][j] = __builtin_amdgcn_mfma_f32_16x16x32_bf16(af[i], bf[j], acc[i][j], 0, 0, 0);
    }
    __syncthreads();
  }

#pragma unroll
  for (int j = 0; j < 4; ++j) {
    int n = n0 + wn + j*16 + l15;
    float bia = bias[n];
#pragma unroll
    for (int i = 0; i < 4; ++i) {
#pragma unroll
      for (int r = 0; r < 4; ++r) {
        int m = m0 + wm + i*16 + quad*4 + r;
        Fo[(size_t)m*EMBED + n] = acc[i][j][r] + bia;
      }
    }
  }
}

// ------------------------------------------------------------------ attention
// One block per (b*h, 128-query tile).  Q held in registers (16 VGPR/lane).
// K and V^T double-buffered in LDS with a 1-barrier-per-tile pipeline:
//   barrier -> issue next tile's gl_lds16 -> compute current tile.
// The counted s_waitcnt (vmcnt(32) in pass 2: 32 newest = this tile's aw
// stores, 4 oldest = prefetch loads) keeps aw stores un-drained across tiles.
// Pass 1: per-LANE online (m,l) stats — no per-tile cross-lane reduction;
// one 4-step butterfly combine after the loop.
__global__ __launch_bounds__(256, 3) void attn(
    const unsigned short* __restrict__ Qw, const unsigned short* __restrict__ Kw,
    const unsigned short* __restrict__ VTw, unsigned short* __restrict__ AP,
    float* __restrict__ AWout)
{
  __shared__ __align__(16) unsigned short Ks[2][64*64];  // 16 KB
  __shared__ __align__(16) unsigned short Vt[2][64*64];  // 16 KB (V^T tiles)
  __shared__ __align__(16) unsigned short Ps[128*72];    // 18 KB (+8 pad)
  const int tid = threadIdx.x;
  const int wid = tid >> 6, lane = tid & 63, quad = lane >> 4, l15 = lane & 15;
  const int bh = blockIdx.x;               // 0..47
  const int q0 = blockIdx.y * 128;
  const unsigned short* Qh  = Qw  + (size_t)bh * SSEQ * HD;
  const unsigned short* Kh  = Kw  + (size_t)bh * SSEQ * HD;
  const unsigned short* VTh = VTw + (size_t)bh * HD * SSEQ;   // [d][s]
  float* aw = AWout + (size_t)bh * SSEQ * SSEQ + (size_t)q0 * SSEQ;

  // Q fragments resident in registers for both passes
  short8 qreg[2][2];
#pragma unroll
  for (int mf = 0; mf < 2; ++mf)
#pragma unroll
    for (int kk = 0; kk < 2; ++kk)
      qreg[mf][kk] = *(const short8*)
          &Qh[(size_t)(q0 + wid*32 + mf*16 + l15)*HD + kk*32 + quad*8];

  float mi[2][4], li[2][4];
#pragma unroll
  for (int mf = 0; mf < 2; ++mf)
#pragma unroll
    for (int r = 0; r < 4; ++r) { mi[mf][r] = -1e30f; li[mf][r] = 0.f; }

  // ---------------- pass 1: per-lane online row stats ----------------
#pragma unroll
  for (int p = 0; p < 2; ++p) {            // prefetch K tile 0
    int f = p*256 + tid;
    gl_lds16(Kh + (size_t)(f >> 3)*HD + (f & 7)*8, &Ks[0][f*8]);
  }
  for (int kt = 0; kt < NT; ++kt) {
    const int cur = kt & 1;
    VM_WAIT0();                            // own prefetch of Ks[cur] landed
    BARRIER();                             // everyone's landed; prev tile reads done
    if (kt + 1 < NT) {                     // issue next tile (hides under compute)
#pragma unroll
      for (int p = 0; p < 2; ++p) {
        int f = p*256 + tid;
        gl_lds16(Kh + (size_t)((kt+1)*64 + (f >> 3))*HD + (f & 7)*8, &Ks[cur^1][f*8]);
      }
    }
    MEMFENCE();

    floatx4 sa[2][4] = {};
#pragma unroll
    for (int kk = 0; kk < 2; ++kk) {
      short8 kf[4];
#pragma unroll
      for (int nf = 0; nf < 4; ++nf)
        kf[nf] = *(const short8*)&Ks[cur][(nf*16 + l15)*64 + kk*32 + quad*8];
#pragma unroll
      for (int mf = 0; mf < 2; ++mf)
#pragma unroll
        for (int nf = 0; nf < 4; ++nf)
          sa[mf][nf] = __builtin_amdgcn_mfma_f32_16x16x32_bf16(qreg[mf][kk], kf[nf], sa[mf][nf], 0, 0, 0);
    }
    // per-lane online update (no shuffles)
#pragma unroll
    for (int mf = 0; mf < 2; ++mf) {
#pragma unroll
      for (int r = 0; r < 4; ++r) {
        float s0 = sa[mf][0][r]*ATT_SCALE, s1 = sa[mf][1][r]*ATT_SCALE;
        float s2 = sa[mf][2][r]*ATT_SCALE, s3 = sa[mf][3][r]*ATT_SCALE;
        float tm = fmaxf(fmaxf(s0, s1), fmaxf(s2, s3));
        float mo = mi[mf][r];
        float mn = fmaxf(mo, tm);
        float e0 = __expf(s0-mn), e1 = __expf(s1-mn);
        float e2 = __expf(s2-mn), e3 = __expf(s3-mn);
        li[mf][r] = li[mf][r]*__expf(mo-mn) + ((e0+e1)+(e2+e3));
        mi[mf][r] = mn;
      }
    }
  }

  // one-time cross-lane combine over the 16 columns (l15 group)
  float rli[2][4];
#pragma unroll
  for (int mf = 0; mf < 2; ++mf) {
#pragma unroll
    for (int r = 0; r < 4; ++r) {
      float m = mi[mf][r], l = li[mf][r];
#pragma unroll
      for (int msk = 1; msk < 16; msk <<= 1) {
        float om = __shfl_xor(m, msk, 16);
        float ol = __shfl_xor(l, msk, 16);
        float mn = fmaxf(m, om);
        l = l*__expf(m-mn) + ol*__expf(om-mn);
        m = mn;
      }
      mi[mf][r]  = m;
      rli[mf][r] = 1.0f / l;
    }
  }

  // ---------------- pass 2: P write + PV ----------------
  floatx4 oa[2][4] = {};
#pragma unroll
  for (int p = 0; p < 2; ++p) {            // prefetch K+V^T tile 0
    int f = p*256 + tid;
    gl_lds16(Kh  + (size_t)(f >> 3)*HD + (f & 7)*8,   &Ks[0][f*8]);
    gl_lds16(VTh + (size_t)(f >> 3)*SSEQ + (f & 7)*8, &Vt[0][f*8]);
  }
  for (int kt = 0; kt < NT; ++kt) {
    const int cur = kt & 1;
    if (kt == 0) { VM_WAIT0(); } else { VM_WAIT32(); }  // drain only the 4 prefetch loads
    BARRIER();
    if (kt + 1 < NT) {
#pragma unroll
      for (int p = 0; p < 2; ++p) {
        int f = p*256 + tid;
        gl_lds16(Kh  + (size_t)((kt+1)*64 + (f >> 3))*HD + (f & 7)*8,       &Ks[cur^1][f*8]);
        gl_lds16(VTh + (size_t)(f >> 3)*SSEQ + (kt+1)*64 + (f & 7)*8,       &Vt[cur^1][f*8]);
      }
    }
    MEMFENCE();

    // QK^T
    floatx4 sa[2][4] = {};
#pragma unroll
    for (int kk = 0; kk < 2; ++kk) {
      short8 kf[4];
#pragma unroll
      for (int nf = 0; nf < 4; ++nf)
        kf[nf] = *(const short8*)&Ks[cur][(nf*16 + l15)*64 + kk*32 + quad*8];
#pragma unroll
      for (int mf = 0; mf < 2; ++mf)
#pragma unroll
        for (int nf = 0; nf < 4; ++nf)
          sa[mf][nf] = __builtin_amdgcn_mfma_f32_16x16x32_bf16(qreg[mf][kk], kf[nf], sa[mf][nf], 0, 0, 0);
    }

    // normalized P: 32 global dword stores (counted by vmcnt(32)) + Ps (bf16)
#pragma unroll
    for (int mf = 0; mf < 2; ++mf) {
#pragma unroll
      for (int nf = 0; nf < 4; ++nf) {
#pragma unroll
        for (int r = 0; r < 4; ++r) {
          float p = __expf(sa[mf][nf][r]*ATT_SCALE - mi[mf][r]) * rli[mf][r];
          int rl = wid*32 + mf*16 + quad*4 + r;
          aw[(size_t)rl*SSEQ + kt*64 + nf*16 + l15] = p;
          Ps[rl*72 + nf*16 + l15] = f2bf(p);
        }
      }
    }

    // PV: O[m][d] += P[m][j] * V[j][d]  (Ps rows wave-private; Vt staged V^T)
#pragma unroll
    for (int kk = 0; kk < 2; ++kk) {
      short8 pf[2], vf[4];
#pragma unroll
      for (int mf = 0; mf < 2; ++mf)
        pf[mf] = *(const short8*)&Ps[(wid*32 + mf*16 + l15)*72 + kk*32 + quad*8];
#pragma unroll
      for (int nd = 0; nd < 4; ++nd)
        vf[nd] = *(const short8*)&Vt[cur][(nd*16 + l15)*64 + kk*32 + quad*8];
#pragma unroll
      for (int mf = 0; mf < 2; ++mf)
#pragma unroll
        for (int nd = 0; nd < 4; ++nd)
          oa[mf][nd] = __builtin_amdgcn_mfma_f32_16x16x32_bf16(pf[mf], vf[nd], oa[mf][nd], 0, 0, 0);
    }
  }

  // epilogue: attn_pre[b, s, h*64+d] bf16
  const int b = bh / NH, h = bh % NH;
#pragma unroll
  for (int mf = 0; mf < 2; ++mf) {
#pragma unroll
    for (int nd = 0; nd < 4; ++nd) {
#pragma unroll
      for (int r = 0; r < 4; ++r) {
        int sq = q0 + wid*32 + mf*16 + quad*4 + r;
        int d  = nd*16 + l15;
        AP[(size_t)(b*SSEQ + sq)*EMBED + h*HD + d] = f2bf(oa[mf][nd][r]);
      }
    }
  }
}

// -------------------------------------------------------------------- launch
extern "C" void kernel_launch(void* const* d_in, const int* in_sizes, int n_in,
                              void* d_out, int out_size, void* d_ws, size_t ws_size,
                              hipStream_t stream) {
  const float* X  = (const float*)d_in[0];
  const float* Wq = (const float*)d_in[1]; const float* bq = (const float*)d_in[2];
  const float* Wk = (const float*)d_in[3]; const float* bk = (const float*)d_in[4];
  const float* Wv = (const float*)d_in[5]; const float* bv = (const float*)d_in[6];
  const float* Wo = (const float*)d_in[7]; const float* bo = (const float*)d_in[8];

  float* outAttn = (float*)d_out;                         // [4,2048,768]
  float* outW    = outAttn + (size_t)TOK * EMBED;         // [4,12,2048,2048]

  // workspace layout (bf16), ~67.6 MB total
  const size_t XN = (size_t)TOK * EMBED;        // 6291456
  const size_t WN = (size_t)EMBED * EMBED;      // 589824
  unsigned short* Xb  = (unsigned short*)d_ws;
  unsigned short* Wqb = Xb  + XN;
  unsigned short* Wkb = Wqb + WN;
  unsigned short* Wvb = Wkb + WN;
  unsigned short* Wob = Wvb + WN;
  unsigned short* Qws = Wob + WN;
  unsigned short* Kws = Qws + XN;
  unsigned short* Vws = Kws + XN;               // V^T [b,h,d,s]
  unsigned short* APs = Vws + XN;               // attn_pre [b,s,h,d]

  // fp32 -> bf16 conversions
  cvtk<<<dim3((unsigned)(XN/4/256)), 256, 0, stream>>>(X,  Xb,  (int)(XN/4));
  cvtk<<<dim3((unsigned)(WN/4/256)), 256, 0, stream>>>(Wq, Wqb, (int)(WN/4));
  cvtk<<<dim3((unsigned)(WN/4/256)), 256, 0, stream>>>(Wk, Wkb, (int)(WN/4));
  cvtk<<<dim3((unsigned)(WN/4/256)), 256, 0, stream>>>(Wv, Wvb, (int)(WN/4));
  cvtk<<<dim3((unsigned)(WN/4/256)), 256, 0, stream>>>(Wo, Wob, (int)(WN/4));

  // QKV projections -> Q/K [b,h,s,d], V^T [b,h,d,s] (all bf16)
  gemm_qkv<<<dim3(EMBED/128, TOK/128, 3), 256, 0, stream>>>(
      Xb, Wqb, Wkb, Wvb, bq, bk, bv, Qws, Kws, Vws);

  // fused attention: attn_weights (fp32, d_out) + attn_pre (bf16, ws)
  attn<<<dim3(BB*NH, SSEQ/128), 256, 0, stream>>>(Qws, Kws, Vws, APs, outW);

  // output projection -> attn_output fp32
  gemm_o<<<dim3(EMBED/128, TOK/128), 256, 0, stream>>>(APs, Wob, bo, outAttn);
}